// Round 12
// baseline (229.229 us; speedup 1.0000x reference)
//
#include <hip/hip_runtime.h>
#include <math.h>

// B=32, S=4096, D=256  (fp32). MAX_LEN=5000.
// out[b,s,d] = nodes[b,s,d] + (s <= num_nodes[b] ? pe[(s-num_nodes[b]) mod 5000, d] : 0)
// pe[p, 2k] = sin(p * div[k]), pe[p, 2k+1] = cos(p * div[k]), div[k] = exp2(-log2(1e4)*2k/256)
//
// Evidence ledger (dispatch = headline - ~155 us harness poison fills):
//  - r7  flat, NT/NT:            65 us     - r8  flat, reg/reg:   69 us
//  - r10 flat, reg/NT:           75 us     - r11 flat, NT/reg:    63 us <- best
//  - r9  flat 4x unroll NT/NT:   66 us     - r5/6 strided:        85 us
//  - copy roofline 268 MB @ 6.3: ~43 us
// Conservation analysis (r5/r6 windows show exactly their own traffic; fills
// show exactly 512 MiB) rules out cross-window writeback debt: our 4.26 TB/s
// is TRUE utilization; HBM has headroom. Policy matrix closed (63-75 band).
// Re-audit: MLP>1 was NEVER established - r6 provably re-serialized
// (VGPR=16), r9's VGPR unobserved and the compiler legally rewrites
// restrict'd load/store pairs sequentially. Little's law at loaded latency
// (~430 ns): need ~11+ KB/CU in flight; MLP=1 @ 54% occ gives ~17 KB -
// marginal. This round: MLP=4 BY CONSTRUCTION - all 4 global_load_dwordx4
// in ONE inline-asm block (indivisible), early-clobber outputs, single
// vmcnt(0) + sched_barrier(0) before use. Geometry=r9, stores=r11 (regular).
// Predict: 45-55 us if MLP was the cap; 63-66 -> plateau is intrinsic,
// declare next round.

typedef float v4f __attribute__((ext_vector_type(4)));

#define BLOCK 256
#define UNROLL 4

__device__ __forceinline__ v4f pe_add(v4f v, int idx, int nn, float f0, float f1) {
    const int s = (idx >> 6) & 4095;       // sequence position (wave-uniform)
    int r = s - nn;                        // no-branch Python mod: r in (-4096, 4096)
    int p = (r < 0) ? r + 5000 : r;        // v_cndmask
    const float pf = (float)p;
    float r0 = pf * f0;  r0 -= floorf(r0); // [0,1) revolutions
    float r1 = pf * f1;  r1 -= floorf(r1);
    const float m = (s <= nn) ? 1.0f : 0.0f;  // v_cndmask mask, no divergence
    v.x = fmaf(m, __builtin_amdgcn_sinf(r0), v.x);  // v_sin_f32: sin(2*pi*r0)
    v.y = fmaf(m, __builtin_amdgcn_cosf(r0), v.y);
    v.z = fmaf(m, __builtin_amdgcn_sinf(r1), v.z);
    v.w = fmaf(m, __builtin_amdgcn_cosf(r1), v.w);
    return v;
}

template <bool EXACT>
__global__ __launch_bounds__(BLOCK) void rpe_kernel(const float* __restrict__ nodes,
                                                    const int* __restrict__ num_nodes,
                                                    float* __restrict__ out,
                                                    const int total4) {
    const int base = blockIdx.x * (BLOCK * UNROLL) + threadIdx.x;

    // d4 identical for all 4 sweeps (sweep stride 256 == 0 mod 64): exp2 once.
    const int d4 = base & 63;
    const float cexp   = -0.051905126482062035f;  // -log2(10000)/256
    const float inv2pi = 0.15915494309189535f;
    const float f0 = exp2f(cexp * (float)(4 * d4)) * inv2pi;
    const float f1 = exp2f(cexp * (float)(4 * d4 + 2)) * inv2pi;

    const v4f* __restrict__ in4  = reinterpret_cast<const v4f*>(nodes);
    v4f* __restrict__       out4 = reinterpret_cast<v4f*>(out);

    if (EXACT) {
        const int i0 = base;
        const int i1 = base + BLOCK;
        const int i2 = base + 2 * BLOCK;
        const int i3 = base + 3 * BLOCK;

        // One block spans 1024 float4s; b = idx>>18 changes every 262144
        // (divisible by 1024) -> whole block shares one b. One s_load.
        const int nn = num_nodes[__builtin_amdgcn_readfirstlane(base >> 18)];

        const v4f* p0 = in4 + i0;
        const v4f* p1 = in4 + i1;
        const v4f* p2 = in4 + i2;
        const v4f* p3 = in4 + i3;

        // Indivisible 4-load cluster: compiler cannot split/reorder/serialize
        // an asm block -> 4 loads in flight per thread, guaranteed (MLP=4).
        v4f v0, v1, v2, v3;
        asm volatile(
            "global_load_dwordx4 %0, %4, off\n\t"
            "global_load_dwordx4 %1, %5, off\n\t"
            "global_load_dwordx4 %2, %6, off\n\t"
            "global_load_dwordx4 %3, %7, off\n\t"
            "s_waitcnt vmcnt(0)"
            : "=&v"(v0), "=&v"(v1), "=&v"(v2), "=&v"(v3)
            : "v"(p0), "v"(p1), "v"(p2), "v"(p3)
            : "memory");
        // rule #18: hipcc may hoist register-only uses past inline-asm
        // waitcnt; fence the scheduler.
        __builtin_amdgcn_sched_barrier(0);

        v0 = pe_add(v0, i0, nn, f0, f1);
        v1 = pe_add(v1, i1, nn, f0, f1);
        v2 = pe_add(v2, i2, nn, f0, f1);
        v3 = pe_add(v3, i3, nn, f0, f1);

        // Regular stores (r11 best policy): retire at LLC acceptance.
        out4[i0] = v0;
        out4[i1] = v1;
        out4[i2] = v2;
        out4[i3] = v3;
    } else {
        #pragma unroll
        for (int j = 0; j < UNROLL; ++j) {
            const int idx = base + j * BLOCK;
            if (idx < total4) {
                v4f v = in4[idx];
                const int nn = num_nodes[__builtin_amdgcn_readfirstlane(idx >> 18)];
                v = pe_add(v, idx, nn, f0, f1);
                out4[idx] = v;
            }
        }
    }
}

extern "C" void kernel_launch(void* const* d_in, const int* in_sizes, int n_in,
                              void* d_out, int out_size, void* d_ws, size_t ws_size,
                              hipStream_t stream) {
    const float* nodes     = (const float*)d_in[0];
    const int*   num_nodes = (const int*)d_in[1];
    float*       out       = (float*)d_out;

    // total float4 elements: 32*4096*256/4 = 8388608 = 8192 * (256*4) exactly
    const int total4 = out_size / 4;
    const int grid   = (total4 + BLOCK * UNROLL - 1) / (BLOCK * UNROLL);

    if (total4 % (BLOCK * UNROLL) == 0) {
        rpe_kernel<true><<<grid, BLOCK, 0, stream>>>(nodes, num_nodes, out, total4);
    } else {
        rpe_kernel<false><<<grid, BLOCK, 0, stream>>>(nodes, num_nodes, out, total4);
    }
}